// Round 20
// baseline (333.625 us; speedup 1.0000x reference)
//
#include <hip/hip_runtime.h>

#define B_ 16
#define N_ 1024
#define F_ 768
#define H_ 128

typedef float f32x4 __attribute__((ext_vector_type(4)));
typedef short s16x8 __attribute__((ext_vector_type(8)));
typedef unsigned short u16;
typedef u16 u16x8 __attribute__((ext_vector_type(8)));
typedef u16 u16x4 __attribute__((ext_vector_type(4)));
typedef unsigned long long u64;

__device__ __forceinline__ u16 f2b(float f) {
  unsigned u = __float_as_uint(f);
  unsigned r = (u + 0x7FFFu + ((u >> 16) & 1u)) >> 16;
  return (u16)r;
}
__device__ __forceinline__ float b2f(u16 u) {
  return __uint_as_float(((unsigned)u) << 16);
}

__device__ __forceinline__ void gload16(const u16* g, u16* l) {
  __builtin_amdgcn_global_load_lds(
      (const __attribute__((address_space(1))) unsigned int*)g,
      (__attribute__((address_space(3))) unsigned int*)l, 16, 0, 0);
}

// fast tanh: (e^{2z}-1)/(e^{2z}+1), z clamped to +-10 (err ~1e-6)
__device__ __forceinline__ float ftanh(float z) {
  z = fminf(fmaxf(z, -10.0f), 10.0f);
  float e = __expf(2.0f * z);
  return (e - 1.0f) / (e + 1.0f);
}

// ---------------------------------------------------------------------------
__device__ __forceinline__ float blockReduceSum256(float v) {
  __shared__ float red[4];
  #pragma unroll
  for (int o = 32; o > 0; o >>= 1) v += __shfl_down(v, o, 64);
  if ((threadIdx.x & 63) == 0) red[threadIdx.x >> 6] = v;
  __syncthreads();
  float r = red[0] + red[1] + red[2] + red[3];
  __syncthreads();
  return r;
}

// ---------------------------------------------------------------------------
// K0 (merged prep): blocks [0,96) transpose-split W1;
// [96,96+BN) degrees+bitmask+adj_bf+rowcnt0+xs-zero
// ---------------------------------------------------------------------------
__global__ __launch_bounds__(256) void k_prep(
    const float* __restrict__ W1, u16* __restrict__ W1h,
    u16* __restrict__ W1m, u16* __restrict__ W1l,
    const float* __restrict__ adj, float* __restrict__ dis_bin,
    float* __restrict__ dr, float* __restrict__ dc, u64* __restrict__ bm,
    u16* __restrict__ adj_bf, int* __restrict__ rowcnt,
    float* __restrict__ xs0, float* __restrict__ xs1) {
  __shared__ float tile[32][33];
  int tid = threadIdx.x;
  if (blockIdx.x < 96) {
    int bid = blockIdx.x;                 // 96 blocks: (H/32)=4 x (F/32)=24
    int bx = bid & 3, by = bid >> 2;
    int tx = tid & 31, ty = tid >> 5;
    int r0 = by * 32, c0 = bx * 32;       // r: F dim, c: H dim
    #pragma unroll
    for (int i = 0; i < 4; ++i)
      tile[ty + i * 8][tx] = W1[(long)(r0 + ty + i * 8) * H_ + (c0 + tx)];
    __syncthreads();
    #pragma unroll
    for (int i = 0; i < 4; ++i) {
      float v = tile[tx][ty + i * 8];
      long o = (long)(c0 + ty + i * 8) * F_ + (r0 + tx);
      u16 h = f2b(v); float r1 = v - b2f(h);
      u16 m = f2b(r1); float r2 = r1 - b2f(m);
      u16 l = f2b(r2);
      W1h[o] = h; W1m[o] = m; W1l[o] = l;
    }
  } else {
    long row = blockIdx.x - 96;
    const float* a = adj + row * N_;
    u16* ab = adj_bf + row * N_;
    float cnt = 0.f, sw = 0.f;
    #pragma unroll
    for (int it = 0; it < 4; ++it) {
      int j = tid + it * 256;
      float v = a[j];
      ab[j] = f2b(v);
      bool nz = (v != 0.0f);
      u64 ball = __ballot(nz);
      if ((tid & 63) == 0) bm[row * 16 + it * 4 + (tid >> 6)] = ball;
      if (nz) { cnt += 1.0f; sw += v; }
    }
    __shared__ float r1[4], r2[4];
    #pragma unroll
    for (int o = 32; o > 0; o >>= 1) { cnt += __shfl_down(cnt, o, 64); sw += __shfl_down(sw, o, 64); }
    if ((tid & 63) == 0) { r1[tid >> 6] = cnt; r2[tid >> 6] = sw; }
    __syncthreads();
    if (tid == 0) {
      float c = r1[0] + r1[1] + r1[2] + r1[3];
      float s = r2[0] + r2[1] + r2[2] + r2[3];
      dis_bin[row] = rsqrtf(c + 1.0f);
      float d = rsqrtf(s + 1.0f);
      dc[row] = d;
      dr[row] = (s > 0.0f) ? d : 0.0f;
      rowcnt[row] = 0;
      xs0[row] = 0.0f;
      xs1[row] = 0.0f;
    }
  }
}

// ---------------------------------------------------------------------------
// G1: P1 = x @ W1 via in-register split-3 (6 products, ~f32 accuracy).
// 64x64 tile (512 blocks = 2/CU), BK=32.
// ---------------------------------------------------------------------------
__global__ __launch_bounds__(256) void mgemmG1(
    const float* __restrict__ X,
    const u16* __restrict__ B0, const u16* __restrict__ B1,
    const u16* __restrict__ B2, float* __restrict__ C) {
  int m0 = blockIdx.y * 64, n0 = blockIdx.x * 64;
  __shared__ __align__(16) u16 As[3][64 * 40];
  __shared__ __align__(16) u16 Bs[3][64 * 32];
  int tid = threadIdx.x;
  int lane = tid & 63, wave = tid >> 6;
  int wr = wave >> 1, wc = wave & 1;
  int kg = lane >> 4, r16 = lane & 15;
  int arow = tid >> 2, aq = (tid & 3) * 8;   // 8 floats per thread
  const float* gx = X + (long)(m0 + arow) * F_ + aq;
  const u16* gb[3] = {
      B0 + (long)(n0 + (tid >> 2)) * F_ + (tid & 3) * 8,
      B1 + (long)(n0 + (tid >> 2)) * F_ + (tid & 3) * 8,
      B2 + (long)(n0 + (tid >> 2)) * F_ + (tid & 3) * 8};
  f32x4 acc[2][2] = {};

  for (int k0 = 0; k0 < F_; k0 += 32) {
    #pragma unroll
    for (int p2 = 0; p2 < 3; ++p2)
      gload16(gb[p2] + k0, &Bs[p2][tid * 8]);
    #pragma unroll
    for (int q = 0; q < 2; ++q) {
      f32x4 v = *(const f32x4*)(gx + k0 + q * 4);
      u16x4 oh, om, ol;
      #pragma unroll
      for (int e = 0; e < 4; ++e) {
        float f = v[e];
        u16 h = f2b(f); float rr1 = f - b2f(h);
        u16 m = f2b(rr1); float rr2 = rr1 - b2f(m);
        u16 l = f2b(rr2);
        oh[e] = h; om[e] = m; ol[e] = l;
      }
      int off = arow * 40 + aq + q * 4;
      *(u16x4*)(&As[0][off]) = oh;
      *(u16x4*)(&As[1][off]) = om;
      *(u16x4*)(&As[2][off]) = ol;
    }
    __syncthreads();
    s16x8 af[3][2], bf[3][2];
    #pragma unroll
    for (int p2 = 0; p2 < 3; ++p2) {
      #pragma unroll
      for (int m = 0; m < 2; ++m)
        af[p2][m] = *(const s16x8*)(&As[p2][(wr * 32 + m * 16 + r16) * 40 + kg * 8]);
      #pragma unroll
      for (int n = 0; n < 2; ++n)
        bf[p2][n] = *(const s16x8*)(&Bs[p2][(wc * 32 + n * 16 + r16) * 32 + kg * 8]);
    }
    #pragma unroll
    for (int m = 0; m < 2; ++m)
      #pragma unroll
      for (int n = 0; n < 2; ++n) {
        acc[m][n] = __builtin_amdgcn_mfma_f32_16x16x32_bf16(af[0][m], bf[0][n], acc[m][n], 0, 0, 0);
        acc[m][n] = __builtin_amdgcn_mfma_f32_16x16x32_bf16(af[0][m], bf[1][n], acc[m][n], 0, 0, 0);
        acc[m][n] = __builtin_amdgcn_mfma_f32_16x16x32_bf16(af[1][m], bf[0][n], acc[m][n], 0, 0, 0);
        acc[m][n] = __builtin_amdgcn_mfma_f32_16x16x32_bf16(af[1][m], bf[1][n], acc[m][n], 0, 0, 0);
        acc[m][n] = __builtin_amdgcn_mfma_f32_16x16x32_bf16(af[0][m], bf[2][n], acc[m][n], 0, 0, 0);
        acc[m][n] = __builtin_amdgcn_mfma_f32_16x16x32_bf16(af[2][m], bf[0][n], acc[m][n], 0, 0, 0);
      }
    __syncthreads();
  }

  #pragma unroll
  for (int m = 0; m < 2; ++m)
    #pragma unroll
    for (int r = 0; r < 4; ++r) {
      int row = m0 + wr * 32 + m * 16 + kg * 4 + r;
      #pragma unroll
      for (int n = 0; n < 2; ++n) {
        int col = n0 + wc * 32 + n * 16 + r16;
        C[(long)row * H_ + col] = acc[m][n][r];
      }
    }
}

// ---------------------------------------------------------------------------
// k_G5G6: merged launch.
// blocks [0,256): G5 = S^T @ x1 (128x64 tile) + cx_bf mirror + xs0 means
// blocks [256,1280): G6' = S^T @ adj^T -> M1t bf16 (128x128 tile, XCD swz)
// ---------------------------------------------------------------------------
__global__ __launch_bounds__(256) void k_G5G6(
    const u16* __restrict__ St, const u16* __restrict__ x1T,
    float* __restrict__ out_cx, u16* __restrict__ cx_bf,
    float* __restrict__ xs0,
    const u16* __restrict__ adjBF, u16* __restrict__ M1t) {
  __shared__ __align__(16) u16 smem[128 * 64];   // 16KB shared by both paths
  const long NN = (long)N_ * N_;
  const long NH = (long)N_ * H_;
  int tid = threadIdx.x;
  int lane = tid & 63, wave = tid >> 6;
  int wr = wave >> 1, wc = wave & 1;
  int kg = lane >> 4, r16 = lane & 15;

  if ((int)blockIdx.x < 256) {
    int id = blockIdx.x;
    int bxg = id & 1, byg = (id >> 1) & 7, bz = id >> 4;
    int m0 = byg * 128, n0 = bxg * 64;
    u16* As = smem;
    u16* Bs = smem + 128 * 32;
    const u16* ga = St + (long)bz * NN + (long)(m0 + (tid >> 2)) * N_ + (tid & 3) * 8;
    const u16* gb = x1T + (long)bz * NH + (long)(n0 + (tid >> 2)) * N_ + (tid & 3) * 8;
    f32x4 acc[4][2] = {};
    for (int k0 = 0; k0 < N_; k0 += 32) {
      gload16(ga + k0, &As[tid * 8]);
      gload16(ga + (long)64 * N_ + k0, &As[2048 + tid * 8]);
      gload16(gb + k0, &Bs[tid * 8]);
      __syncthreads();
      s16x8 af[4], bf[2];
      #pragma unroll
      for (int m = 0; m < 4; ++m)
        af[m] = *(const s16x8*)(&As[(wr * 64 + m * 16 + r16) * 32 + kg * 8]);
      #pragma unroll
      for (int n = 0; n < 2; ++n)
        bf[n] = *(const s16x8*)(&Bs[(wc * 32 + n * 16 + r16) * 32 + kg * 8]);
      #pragma unroll
      for (int m = 0; m < 4; ++m)
        #pragma unroll
        for (int n = 0; n < 2; ++n)
          acc[m][n] = __builtin_amdgcn_mfma_f32_16x16x32_bf16(af[m], bf[n], acc[m][n], 0, 0, 0);
      __syncthreads();
    }
    #pragma unroll
    for (int m = 0; m < 4; ++m)
      #pragma unroll
      for (int r = 0; r < 4; ++r) {
        int row = m0 + wr * 64 + m * 16 + kg * 4 + r;
        float part = 0.f;
        #pragma unroll
        for (int n = 0; n < 2; ++n) {
          int col = n0 + wc * 32 + n * 16 + r16;
          long cidx = (long)bz * NH + (long)row * H_ + col;
          float v = acc[m][n][r];
          out_cx[cidx] = v;
          cx_bf[cidx] = f2b(v);
          part += v;
        }
        #pragma unroll
        for (int o2 = 1; o2 < 16; o2 <<= 1) part += __shfl_xor(part, o2, 64);
        if (r16 == 0) atomicAdd(&xs0[(long)bz * N_ + row], part * (1.0f / H_));
      }
  } else {
    int lin = (int)blockIdx.x - 256;
    int swz = (lin & 7) * 128 + (lin >> 3);
    int bx = swz & 7, by = (swz >> 3) & 7, bz = swz >> 6;
    int m0 = by * 128, n0 = bx * 128;
    u16* As = smem;
    u16* Bs = smem + 128 * 32;
    const u16* ga = St + (long)bz * NN + (long)(m0 + (tid >> 2)) * N_ + (tid & 3) * 8;
    const u16* gb = adjBF + (long)bz * NN + (long)(n0 + (tid >> 2)) * N_ + (tid & 3) * 8;
    f32x4 acc[4][4] = {};
    for (int k0 = 0; k0 < N_; k0 += 32) {
      gload16(ga + k0, &As[tid * 8]);
      gload16(ga + (long)64 * N_ + k0, &As[2048 + tid * 8]);
      gload16(gb + k0, &Bs[tid * 8]);
      gload16(gb + (long)64 * N_ + k0, &Bs[2048 + tid * 8]);
      __syncthreads();
      s16x8 af[4], bfr[4];
      #pragma unroll
      for (int m = 0; m < 4; ++m)
        af[m] = *(const s16x8*)(&As[(wr * 64 + m * 16 + r16) * 32 + kg * 8]);
      #pragma unroll
      for (int n = 0; n < 4; ++n)
        bfr[n] = *(const s16x8*)(&Bs[(wc * 64 + n * 16 + r16) * 32 + kg * 8]);
      #pragma unroll
      for (int m = 0; m < 4; ++m)
        #pragma unroll
        for (int n = 0; n < 4; ++n)
          acc[m][n] = __builtin_amdgcn_mfma_f32_16x16x32_bf16(af[m], bfr[n], acc[m][n], 0, 0, 0);
      __syncthreads();
    }
    #pragma unroll
    for (int m = 0; m < 4; ++m)
      #pragma unroll
      for (int r = 0; r < 4; ++r) {
        int row = m0 + wr * 64 + m * 16 + kg * 4 + r;
        #pragma unroll
        for (int n = 0; n < 4; ++n) {
          int col = n0 + wc * 64 + n * 16 + r16;
          M1t[(long)bz * NN + (long)row * N_ + col] = f2b(acc[m][n][r]);
        }
      }
  }
}

// ---------------------------------------------------------------------------
// K2: x1 = relu(dis_i*(sum_{bit j} dis_j*P1_j + dis_i*P1_i) + b1)
// bitmask compaction; 8-team f32x4 gather; fused t[row] = x1_row . Watt
// ---------------------------------------------------------------------------
__global__ __launch_bounds__(256) void k_spmm_relu(
    const u64* __restrict__ bm, const float* __restrict__ P1,
    const float* __restrict__ dis_bin, const float* __restrict__ b1,
    const float* __restrict__ Watt, float* __restrict__ x1,
    float* __restrict__ t) {
  long row = blockIdx.x;
  int b = (int)(row >> 10), i = (int)(row & 1023);
  const float* Pb = P1 + (long)b * (long)N_ * H_;
  const float* db = dis_bin + (long)b * N_;
  __shared__ int idxs[N_];
  __shared__ int wtot[4];
  __shared__ float accs[8][H_];
  int tid = threadIdx.x;
  int wid = tid >> 6, lane = tid & 63;
  int base = tid * 4;
  u64 word = bm[row * 16 + (tid >> 4)];
  int sh = base & 63;
  int f0 = (int)((word >> sh) & 1), f1 = (int)((word >> (sh + 1)) & 1);
  int f2 = (int)((word >> (sh + 2)) & 1), f3 = (int)((word >> (sh + 3)) & 1);
  int c0 = f0 + f1 + f2 + f3;
  int inc = c0;
  #pragma unroll
  for (int o = 1; o < 64; o <<= 1) {
    int v = __shfl_up(inc, o, 64);
    if (lane >= o) inc += v;
  }
  if (lane == 63) wtot[wid] = inc;
  __syncthreads();
  int wbase = 0;
  #pragma unroll
  for (int w = 0; w < 4; ++w) wbase += (w < wid) ? wtot[w] : 0;
  int pos = wbase + inc - c0;
  int n = wtot[0] + wtot[1] + wtot[2] + wtot[3];
  if (f0) idxs[pos++] = base;
  if (f1) idxs[pos++] = base + 1;
  if (f2) idxs[pos++] = base + 2;
  if (f3) idxs[pos++] = base + 3;
  __syncthreads();
  // 8-team gather: team tm handles rows u = tm, tm+8, ...; lane covers 4 ch
  int tm = tid >> 5, c4 = (tid & 31) * 4;
  f32x4 acc4 = {0.f, 0.f, 0.f, 0.f};
  for (int u = tm; u < n; u += 8) {
    int j = idxs[u];
    float w = db[j];
    f32x4 pv = *(const f32x4*)(Pb + (long)j * H_ + c4);
    acc4[0] += w * pv[0];
    acc4[1] += w * pv[1];
    acc4[2] += w * pv[2];
    acc4[3] += w * pv[3];
  }
  *(f32x4*)(&accs[tm][c4]) = acc4;
  __syncthreads();
  float v = 0.f;
  if (tid < H_) {
    int c = tid;
    float tot = 0.f;
    #pragma unroll
    for (int t8 = 0; t8 < 8; ++t8) tot += accs[t8][c];
    float di = db[i];
    tot += di * Pb[(long)i * H_ + c];
    v = fmaxf(di * tot + b1[c], 0.0f);
    x1[row * H_ + c] = v;
  }
  float prod = (tid < H_) ? v * Watt[tid] : 0.f;
  float s = blockReduceSum256(prod);
  if (tid == 0) t[row] = s;
}

// ---------------------------------------------------------------------------
// K6: blocks [0,16): alpha (inline from bitmask + LDS dt) + top-k cut + mask.
// blocks [16,2064): x1 -> x1T transpose. blocks [2064,2160): W2 -> W2T.
// ---------------------------------------------------------------------------
__global__ __launch_bounds__(1024) void k_alphacut(
    const u64* __restrict__ bm, const float* __restrict__ dis_bin,
    const float* __restrict__ t, const float* __restrict__ batt,
    const int* __restrict__ num_sent, const int* __restrict__ nout,
    float* __restrict__ index_mask, float* __restrict__ ca,
    const float* __restrict__ x1, u16* __restrict__ x1T,
    const float* __restrict__ W2, u16* __restrict__ W2T) {
  int tid = threadIdx.x;
  if (blockIdx.x >= 16) {
    // 1024-thread 32x32 transpose tile: one element per thread
    __shared__ float tile[32][33];
    int tx = tid & 31, ty = tid >> 5;
    if (blockIdx.x < 16 + 2048) {
      int id2 = blockIdx.x - 16;          // x1 [N][H] -> x1T [H][N], per batch
      int bx = id2 & 3, by = (id2 >> 2) & 31, bz = id2 >> 7;
      long NH = (long)N_ * H_;
      const float* Xb = x1 + (long)bz * NH;
      u16* Yb = x1T + (long)bz * NH;
      int r0 = by * 32, c0 = bx * 32;
      tile[ty][tx] = Xb[(long)(r0 + ty) * H_ + (c0 + tx)];
      __syncthreads();
      Yb[(long)(c0 + ty) * N_ + (r0 + tx)] = f2b(tile[tx][ty]);
    } else {
      int id3 = blockIdx.x - 16 - 2048;   // W2 [H][F] -> W2T [F][H]
      int bx = id3 % 24, by = id3 / 24;
      int r0 = by * 32, c0 = bx * 32;     // r: H dim, c: F dim
      tile[ty][tx] = W2[(long)(r0 + ty) * F_ + (c0 + tx)];
      __syncthreads();
      W2T[(long)(c0 + ty) * H_ + (r0 + tx)] = f2b(tile[tx][ty]);
    }
    return;
  }
  int b = blockIdx.x;
  __shared__ u64 keys[N_];
  __shared__ u64 red[N_];
  __shared__ float dt[N_];
  float di = dis_bin[(long)b * N_ + tid];
  float ti = t[(long)b * N_ + tid];
  dt[tid] = di * ti;
  __syncthreads();
  float s = 0.f;
  const u64* bmr = bm + ((long)b * N_ + tid) * 16;
  #pragma unroll
  for (int w = 0; w < 16; ++w) {
    u64 word = bmr[w];
    int base = w * 64;
    while (word) {
      int j = (int)__builtin_ctzll(word);
      word &= word - 1;
      s += dt[base + j];
    }
  }
  float pre = di * (s + di * ti) + batt[0];
  float z = pre * pre;
  float av = 1.0f / (1.0f + expf(-z));

  int ns = num_sent[b];
  unsigned bits = __float_as_uint(av);
  u64 keyFull = ((u64)bits << 32) | (u64)(0xFFFFFFFFu - (unsigned)tid);
  keys[tid] = (tid < ns) ? keyFull : 0ULL;
  __syncthreads();
  int k = nout[0];
  u64 cutkey = 0;
  for (int r = 0; r < k; ++r) {
    red[tid] = keys[tid];
    __syncthreads();
    for (int off = 512; off > 0; off >>= 1) {
      if (tid < off) { u64 o = red[tid + off]; if (o > red[tid]) red[tid] = o; }
      __syncthreads();
    }
    u64 mx = red[0];
    __syncthreads();
    if (r == k - 1) cutkey = mx;
    else if (keys[tid] == mx) keys[tid] = 0ULL;
    __syncthreads();
  }
  float cutalpha = __uint_as_float((unsigned)(cutkey >> 32));
  index_mask[(long)b * N_ + tid] = (keyFull >= cutkey) ? 1.0f : 0.0f;
  ca[(long)b * N_ + tid] = fmaxf(av + 1e-7f - cutalpha, 0.0f);
}

// ---------------------------------------------------------------------------
// K7 (fused): S build + L1 row-normalize + direct St emission.
// One block per 32-row group (512 blocks). Pass 1: row sums (wave-per-row,
// coalesced). Pass 2: recompute (adj_bf L2-hot), write S coalesced + St via
// LDS-staged 32x32 tiles (same 64B-segment pattern as the old convTS).
// ---------------------------------------------------------------------------
__global__ __launch_bounds__(256) void k_build_S2(
    const u16* __restrict__ abf, const float* __restrict__ dr,
    const float* __restrict__ dc, const float* __restrict__ ca,
    float* __restrict__ S, u16* __restrict__ St) {
  int blk = blockIdx.x;
  int b = blk >> 5, g = blk & 31;
  int r0 = g * 32;
  const long NN = (long)N_ * N_;
  const u16* ab = abf + (long)b * NN;
  __shared__ float dcs[N_], cas[N_];
  __shared__ float drs[32], rsum[32];
  __shared__ float tile[32][33];
  int tid = threadIdx.x;
  for (int j = tid; j < N_; j += 256) {
    dcs[j] = dc[(long)b * N_ + j];
    cas[j] = ca[(long)b * N_ + j];
  }
  if (tid < 32) drs[tid] = dr[(long)b * N_ + r0 + tid];
  __syncthreads();
  // pass 1: row sums (wave wid handles local rows wid, wid+4, ...)
  int wid = tid >> 6, lane = tid & 63;
  #pragma unroll
  for (int it = 0; it < 8; ++it) {
    int rl = wid + it * 4;
    int i = r0 + rl;
    float dri = drs[rl];
    const u16* arow = ab + (long)i * N_;
    float s = 0.f;
    #pragma unroll
    for (int e = 0; e < 16; ++e) {
      int j = lane + e * 64;
      float avv = b2f(arow[j]) + ((j == i) ? 1.0f : 0.0f);
      s += dri * avv * dcs[j] * cas[j];
    }
    #pragma unroll
    for (int o = 32; o > 0; o >>= 1) s += __shfl_down(s, o, 64);
    if (lane == 0) rsum[rl] = s;
  }
  __syncthreads();
  // pass 2: S + St
  int tx = tid & 31, ty = tid >> 5;
  float* Sb = S + (long)b * NN;
  u16* Stb = St + (long)b * NN;
  for (int ct = 0; ct < 32; ++ct) {
    int c0 = ct * 32;
    #pragma unroll
    for (int i2 = 0; i2 < 4; ++i2) {
      int rl = ty + i2 * 8;
      int i = r0 + rl;
      int j = c0 + tx;
      float avv = b2f(ab[(long)i * N_ + j]) + ((j == i) ? 1.0f : 0.0f);
      float v = drs[rl] * avv * dcs[j] * cas[j];
      float denom = fmaxf(rsum[rl], 1e-12f);
      float outv = v / denom;
      Sb[(long)i * N_ + j] = outv;
      tile[rl][tx] = outv;
    }
    __syncthreads();
    #pragma unroll
    for (int i2 = 0; i2 < 4; ++i2) {
      int jl = ty + i2 * 8;
      Stb[(long)(c0 + jl) * N_ + (r0 + tx)] = f2b(tile[tx][jl]);
    }
    __syncthreads();
  }
}

// ---------------------------------------------------------------------------
// Big MFMA GEMM: 128x128 tile, BK=32, global_load_lds staging, XCD swizzle.
// B-operand rows (length K) at stride ldb (batch offset sB).
// MODE 2: floorq + rowcnt + cbin(diag+1) |
// 3: f32 ftanh(rsqrt(1+cnt[row])*acc + bias[col]) + xs1 atomics |
// 5: bf16 f2b(rsqrt(1+cnt[col])*acc)
// ---------------------------------------------------------------------------
template<int MODE>
__global__ __launch_bounds__(256) void mgemm(
    const u16* __restrict__ A, const u16* __restrict__ Bt, void* __restrict__ Cv,
    int M, int N, int K, long sA, long sB, long sC, long ldb,
    const int* __restrict__ cnt, const float* __restrict__ bias,
    int* __restrict__ rowcnt, u16* __restrict__ cbin,
    float* __restrict__ xsum) {
  // XCD-aware bijective chunked remap (total blocks divisible by 8)
  int gx = gridDim.x, gy = gridDim.y;
  int lin = (blockIdx.z * gy + blockIdx.y) * gx + blockIdx.x;
  int total = gx * gy * gridDim.z;
  int chunk = total >> 3;
  int swz = (lin & 7) * chunk + (lin >> 3);
  int bx = swz % gx; int t2 = swz / gx; int by = t2 % gy; int bz = t2 / gy;

  int m0 = by * 128, n0 = bx * 128;
  const u16* Ab = A + (long)bz * sA + (long)m0 * K;
  const u16* Bb = Bt + (long)bz * sB + (long)n0 * ldb;
  __shared__ __align__(16) u16 As[128 * 32];
  __shared__ __align__(16) u16 Bs[128 * 32];
  int tid = threadIdx.x;
  int lane = tid & 63, wave = tid >> 6;
  int wr = wave >> 1, wc = wave & 1;
  int kg = lane >> 4, r16 = lane & 15;
  const u16* ga = Ab + (long)(tid >> 2) * K + (tid & 3) * 8;
  const u16* gb = Bb + (long)(tid >> 2) * ldb + (tid & 3) * 8;
  f32x4 acc[4][4] = {};

  for (int k0 = 0; k0 < K; k0 += 32) {
    gload16(ga + k0, &As[tid * 8]);
    gload16(ga + (long)64 * K + k0, &As[2048 + tid * 8]);
    gload16(gb + k0, &Bs[tid * 8]);
    gload16(gb + (long)64 * ldb + k0, &Bs[2048 + tid * 8]);
    __syncthreads();
    s16x8 af[4], bfr[4];
    #pragma unroll
    for (int m = 0; m < 4; ++m)
      af[m] = *(const s16x8*)(&As[(wr * 64 + m * 16 + r16) * 32 + kg * 8]);
    #pragma unroll
    for (int n = 0; n < 4; ++n)
      bfr[n] = *(const s16x8*)(&Bs[(wc * 64 + n * 16 + r16) * 32 + kg * 8]);
    #pragma unroll
    for (int m = 0; m < 4; ++m)
      #pragma unroll
      for (int n = 0; n < 4; ++n)
        acc[m][n] = __builtin_amdgcn_mfma_f32_16x16x32_bf16(af[m], bfr[n], acc[m][n], 0, 0, 0);
    __syncthreads();
  }

  if constexpr (MODE == 2) {
    int* cntl = (int*)As;
    if (tid < 128) cntl[tid] = 0;
    __syncthreads();
    #pragma unroll
    for (int m = 0; m < 4; ++m) {
      #pragma unroll
      for (int r = 0; r < 4; ++r) {
        int lrow = wr * 64 + m * 16 + kg * 4 + r;
        int row = m0 + lrow;
        int nz = 0;
        #pragma unroll
        for (int n = 0; n < 4; ++n) {
          int col = n0 + wc * 64 + n * 16 + r16;
          float q = floorf(acc[m][n][r] * 10000.0f) / 10000.0f;
          long cidx = (long)bz * sC + (long)row * N + col;
          ((float*)Cv)[cidx] = q;
          bool qnz = (q != 0.0f);
          u16 bv;
          if (row == col) bv = qnz ? (u16)0x4000 : (u16)0x3F80;  // bin+I diag
          else            bv = qnz ? (u16)0x3F80 : (u16)0;
          cbin[cidx] = bv;
          nz += qnz ? 1 : 0;
        }
        atomicAdd(&cntl[lrow], nz);
      }
    }
    __syncthreads();
    if (tid < 128) atomicAdd(&rowcnt[(long)bz * N_ + m0 + tid], cntl[tid]);
    return;
  }

  #pragma unroll
  for (int m = 0; m < 4; ++m) {
    #pragma unroll
    for (int r = 0; r < 4; ++r) {
      int row = m0 + wr * 64 + m * 16 + kg * 4 + r;
      float sc = 0.f;
      if constexpr (MODE == 3)
        sc = rsqrtf(1.0f + (float)cnt[(long)bz * N_ + row]);
      float part = 0.f;
      #pragma unroll
      for (int n = 0; n < 4; ++n) {
        int col = n0 + wc * 64 + n * 16 + r16;
        float v = acc[m][n][r];
        long cidx = (long)bz * sC + (long)row * N + col;
        if constexpr (MODE == 3) {
          float th = ftanh(sc * v + bias[col]);
          ((float*)Cv)[cidx] = th;
          part += th;
        } else if constexpr (MODE == 5) {
          float scc = rsqrtf(1.0f + (float)cnt[col]);
          ((u16*)Cv)[cidx] = f2b(scc * v);
        } else {
          ((float*)Cv)[cidx] = v;
        }
      }
      if constexpr (MODE == 3) {
        #pragma unroll
        for (int o2 = 1; o2 < 16; o2 <<= 1) part += __shfl_xor(part, o2, 64);
        if (r16 == 0) atomicAdd(&xsum[(long)bz * N_ + row], part * (1.0f / F_));
      }
    }
  }
}

// ---------------------------------------------------------------------------
extern "C" void kernel_launch(void* const* d_in, const int* in_sizes, int n_in,
                              void* d_out, int out_size, void* d_ws, size_t ws_size,
                              hipStream_t stream) {
  const float* x     = (const float*)d_in[0];
  const float* adj   = (const float*)d_in[1];
  const int*   nsent = (const int*)d_in[2];
  const float* W1    = (const float*)d_in[3];
  const float* b1    = (const float*)d_in[4];
  const float* Watt  = (const float*)d_in[5];
  const float* batt  = (const float*)d_in[6];
  const float* W2    = (const float*)d_in[7];
  const float* b2    = (const float*)d_in[8];
  const int*   nout  = (const int*)d_in[9];

  const long NN = (long)N_ * N_;
  const long NH = (long)N_ * H_;
  const long NF = (long)N_ * F_;
  const int BN = B_ * N_;

  // output layout (flat concat, f32)
  float* out_x2   = (float*)d_out;
  float* out_cx   = out_x2 + (long)B_ * NF;
  float* out_cadj = out_cx + (long)B_ * NH;
  float* out_S    = out_cadj + (long)B_ * NN;
  float* out_im   = out_S + (long)B_ * NN;
  float* out_xs0  = out_im + BN;
  float* out_xs1  = out_xs0 + BN;

  // workspace
  char* wsb = (char*)d_ws;
  float* P1      = (float*)wsb;
  float* x1      = P1 + (long)B_ * NH;
  float* t       = x1 + (long)B_ * NH;
  float* alpha   = t + BN;
  float* dis_bin = alpha + BN;
  float* dr      = dis_bin + BN;
  float* dc      = dr + BN;
  float* ca      = dc + BN;
  int*   rowcnt  = (int*)(ca + BN);
  u64*   bm      = (u64*)(rowcnt + BN);       // 2MB bitmask
  char*  p       = (char*)(bm + (long)BN * 16);
  p = (char*)(((size_t)p + 255) & ~(size_t)255);
  u16* W1h   = (u16*)p;  p += (long)H_ * F_ * 2;
  u16* W1m   = (u16*)p;  p += (long)H_ * F_ * 2;
  u16* W1l   = (u16*)p;  p += (long)H_ * F_ * 2;
  u16* W2T   = (u16*)p;  p += (long)H_ * F_ * 2;
  u16* PT    = (u16*)p;  p += (long)B_ * NH * 2;   // x1T
  u16* St    = (u16*)p;  p += (long)B_ * NN * 2;   // St -> P2T
  u16* wsB   = (u16*)p;  p += (long)B_ * NN * 2;   // cbin
  u16* cx_bf = (u16*)P1;         // P1 dead after spmm
  u16* x1T   = PT;
  u16* adjBF = (u16*)out_cadj;   // lives in out_cadj region until G7' writes it
  u16* cbin  = wsB;              // written by G7'
  u16* P2T   = St;               // St dead after G7'
  u16* M1t   = (u16*)out_x2;     // scratch in unwritten output region (32MB)
  (void)alpha;

  // K0: transpose-split W1 + degrees/bitmask/adj_bf/rowcnt/xs-zero
  k_prep<<<dim3(96 + BN), dim3(256), 0, stream>>>(
      W1, W1h, W1m, W1l,
      adj, dis_bin, dr, dc, bm, adjBF, rowcnt, out_xs0, out_xs1);

  // G1: P1raw = x @ W1  (in-register split-3 from f32 x; 64x64 tile)
  mgemmG1<<<dim3(H_ / 64, BN / 64, 1), dim3(256), 0, stream>>>(
      x, W1h, W1m, W1l, P1);

  // K2: x1 + fused t (bitmask, 8-team f32x4 gather)
  k_spmm_relu<<<dim3(BN), dim3(256), 0, stream>>>(bm, P1, dis_bin, b1, Watt, x1, t);

  // alpha (inline) + top-k cut/mask, co-scheduled with x1T/W2T transposes
  k_alphacut<<<dim3(16 + 2048 + 96), dim3(1024), 0, stream>>>(
      bm, dis_bin, t, batt, nsent, nout, out_im, ca, x1, x1T, W2, W2T);

  // S + St fused (S from bf16 adj; St via LDS-staged tiles)
  k_build_S2<<<dim3(B_ * 32), dim3(256), 0, stream>>>(
      adjBF, dr, dc, ca, out_S, St);

  // G5+G6' merged: coarse_x (+cx_bf, xs0) and M1t = (adj @ S)^T
  k_G5G6<<<dim3(256 + 1024), dim3(256), 0, stream>>>(
      St, x1T, out_cx, cx_bf, out_xs0, adjBF, M1t);

  // G7': coarse_adj = floorq(S^T @ M1) + rowcnt + cbin(diag+1)
  mgemm<2><<<dim3(N_ / 128, N_ / 128, B_), dim3(256), 0, stream>>>(
      St, M1t, out_cadj, N_, N_, N_, NN, NN, NN, N_, nullptr, nullptr, rowcnt,
      cbin, nullptr);

  // G8' (transposed role): P2T[f][r] = f2b(rsqrt(1+cnt[r]) * (W2T[f] . cx_bf[r]))
  mgemm<5><<<dim3(BN / 128, F_ / 128, 1), dim3(256), 0, stream>>>(
      W2T, cx_bf, P2T, F_, BN, H_, 0, 0, 0, H_, rowcnt, nullptr, nullptr,
      nullptr, nullptr);

  // G9: x2 = ftanh(rsqrt(1+cnt[row]) * (cbin' @ P2) + b2) + xs1 row-means
  mgemm<3><<<dim3(F_ / 128, N_ / 128, B_), dim3(256), 0, stream>>>(
      cbin, P2T, out_x2, N_, F_, N_, NN, N_, NF, (long)BN, rowcnt, b2,
      nullptr, nullptr, out_xs1);
}

// Round 21
// 328.034 us; speedup vs baseline: 1.0170x; 1.0170x over previous
//
#include <hip/hip_runtime.h>

#define B_ 16
#define N_ 1024
#define F_ 768
#define H_ 128

typedef float f32x4 __attribute__((ext_vector_type(4)));
typedef short s16x8 __attribute__((ext_vector_type(8)));
typedef unsigned short u16;
typedef u16 u16x8 __attribute__((ext_vector_type(8)));
typedef u16 u16x4 __attribute__((ext_vector_type(4)));
typedef unsigned long long u64;

__device__ __forceinline__ u16 f2b(float f) {
  unsigned u = __float_as_uint(f);
  unsigned r = (u + 0x7FFFu + ((u >> 16) & 1u)) >> 16;
  return (u16)r;
}
__device__ __forceinline__ float b2f(u16 u) {
  return __uint_as_float(((unsigned)u) << 16);
}

__device__ __forceinline__ void gload16(const u16* g, u16* l) {
  __builtin_amdgcn_global_load_lds(
      (const __attribute__((address_space(1))) unsigned int*)g,
      (__attribute__((address_space(3))) unsigned int*)l, 16, 0, 0);
}

// fast tanh: (e^{2z}-1)/(e^{2z}+1), z clamped to +-10 (err ~1e-6)
__device__ __forceinline__ float ftanh(float z) {
  z = fminf(fmaxf(z, -10.0f), 10.0f);
  float e = __expf(2.0f * z);
  return (e - 1.0f) / (e + 1.0f);
}

// ---------------------------------------------------------------------------
__device__ __forceinline__ float blockReduceSum256(float v) {
  __shared__ float red[4];
  #pragma unroll
  for (int o = 32; o > 0; o >>= 1) v += __shfl_down(v, o, 64);
  if ((threadIdx.x & 63) == 0) red[threadIdx.x >> 6] = v;
  __syncthreads();
  float r = red[0] + red[1] + red[2] + red[3];
  __syncthreads();
  return r;
}

// ---------------------------------------------------------------------------
// K0 (merged prep): blocks [0,96) transpose-split W1;
// [96,96+BN) degrees+bitmask+adj_bf+rowcnt0+xs-zero
// ---------------------------------------------------------------------------
__global__ __launch_bounds__(256) void k_prep(
    const float* __restrict__ W1, u16* __restrict__ W1h,
    u16* __restrict__ W1m, u16* __restrict__ W1l,
    const float* __restrict__ adj, float* __restrict__ dis_bin,
    float* __restrict__ dr, float* __restrict__ dc, u64* __restrict__ bm,
    u16* __restrict__ adj_bf, int* __restrict__ rowcnt,
    float* __restrict__ xs0, float* __restrict__ xs1) {
  __shared__ float tile[32][33];
  int tid = threadIdx.x;
  if (blockIdx.x < 96) {
    int bid = blockIdx.x;                 // 96 blocks: (H/32)=4 x (F/32)=24
    int bx = bid & 3, by = bid >> 2;
    int tx = tid & 31, ty = tid >> 5;
    int r0 = by * 32, c0 = bx * 32;       // r: F dim, c: H dim
    #pragma unroll
    for (int i = 0; i < 4; ++i)
      tile[ty + i * 8][tx] = W1[(long)(r0 + ty + i * 8) * H_ + (c0 + tx)];
    __syncthreads();
    #pragma unroll
    for (int i = 0; i < 4; ++i) {
      float v = tile[tx][ty + i * 8];
      long o = (long)(c0 + ty + i * 8) * F_ + (r0 + tx);
      u16 h = f2b(v); float r1 = v - b2f(h);
      u16 m = f2b(r1); float r2 = r1 - b2f(m);
      u16 l = f2b(r2);
      W1h[o] = h; W1m[o] = m; W1l[o] = l;
    }
  } else {
    long row = blockIdx.x - 96;
    const float* a = adj + row * N_;
    u16* ab = adj_bf + row * N_;
    float cnt = 0.f, sw = 0.f;
    #pragma unroll
    for (int it = 0; it < 4; ++it) {
      int j = tid + it * 256;
      float v = a[j];
      ab[j] = f2b(v);
      bool nz = (v != 0.0f);
      u64 ball = __ballot(nz);
      if ((tid & 63) == 0) bm[row * 16 + it * 4 + (tid >> 6)] = ball;
      if (nz) { cnt += 1.0f; sw += v; }
    }
    __shared__ float r1[4], r2[4];
    #pragma unroll
    for (int o = 32; o > 0; o >>= 1) { cnt += __shfl_down(cnt, o, 64); sw += __shfl_down(sw, o, 64); }
    if ((tid & 63) == 0) { r1[tid >> 6] = cnt; r2[tid >> 6] = sw; }
    __syncthreads();
    if (tid == 0) {
      float c = r1[0] + r1[1] + r1[2] + r1[3];
      float s = r2[0] + r2[1] + r2[2] + r2[3];
      dis_bin[row] = rsqrtf(c + 1.0f);
      float d = rsqrtf(s + 1.0f);
      dc[row] = d;
      dr[row] = (s > 0.0f) ? d : 0.0f;
      rowcnt[row] = 0;
      xs0[row] = 0.0f;
      xs1[row] = 0.0f;
    }
  }
}

// ---------------------------------------------------------------------------
// G1: P1 = x @ W1 via in-register split-3 (6 products, ~f32 accuracy).
// 64x64 tile (512 blocks = 2/CU), BK=32.
// ---------------------------------------------------------------------------
__global__ __launch_bounds__(256) void mgemmG1(
    const float* __restrict__ X,
    const u16* __restrict__ B0, const u16* __restrict__ B1,
    const u16* __restrict__ B2, float* __restrict__ C) {
  int m0 = blockIdx.y * 64, n0 = blockIdx.x * 64;
  __shared__ __align__(16) u16 As[3][64 * 40];
  __shared__ __align__(16) u16 Bs[3][64 * 32];
  int tid = threadIdx.x;
  int lane = tid & 63, wave = tid >> 6;
  int wr = wave >> 1, wc = wave & 1;
  int kg = lane >> 4, r16 = lane & 15;
  int arow = tid >> 2, aq = (tid & 3) * 8;   // 8 floats per thread
  const float* gx = X + (long)(m0 + arow) * F_ + aq;
  const u16* gb[3] = {
      B0 + (long)(n0 + (tid >> 2)) * F_ + (tid & 3) * 8,
      B1 + (long)(n0 + (tid >> 2)) * F_ + (tid & 3) * 8,
      B2 + (long)(n0 + (tid >> 2)) * F_ + (tid & 3) * 8};
  f32x4 acc[2][2] = {};

  for (int k0 = 0; k0 < F_; k0 += 32) {
    #pragma unroll
    for (int p2 = 0; p2 < 3; ++p2)
      gload16(gb[p2] + k0, &Bs[p2][tid * 8]);
    #pragma unroll
    for (int q = 0; q < 2; ++q) {
      f32x4 v = *(const f32x4*)(gx + k0 + q * 4);
      u16x4 oh, om, ol;
      #pragma unroll
      for (int e = 0; e < 4; ++e) {
        float f = v[e];
        u16 h = f2b(f); float rr1 = f - b2f(h);
        u16 m = f2b(rr1); float rr2 = rr1 - b2f(m);
        u16 l = f2b(rr2);
        oh[e] = h; om[e] = m; ol[e] = l;
      }
      int off = arow * 40 + aq + q * 4;
      *(u16x4*)(&As[0][off]) = oh;
      *(u16x4*)(&As[1][off]) = om;
      *(u16x4*)(&As[2][off]) = ol;
    }
    __syncthreads();
    s16x8 af[3][2], bf[3][2];
    #pragma unroll
    for (int p2 = 0; p2 < 3; ++p2) {
      #pragma unroll
      for (int m = 0; m < 2; ++m)
        af[p2][m] = *(const s16x8*)(&As[p2][(wr * 32 + m * 16 + r16) * 40 + kg * 8]);
      #pragma unroll
      for (int n = 0; n < 2; ++n)
        bf[p2][n] = *(const s16x8*)(&Bs[p2][(wc * 32 + n * 16 + r16) * 32 + kg * 8]);
    }
    #pragma unroll
    for (int m = 0; m < 2; ++m)
      #pragma unroll
      for (int n = 0; n < 2; ++n) {
        acc[m][n] = __builtin_amdgcn_mfma_f32_16x16x32_bf16(af[0][m], bf[0][n], acc[m][n], 0, 0, 0);
        acc[m][n] = __builtin_amdgcn_mfma_f32_16x16x32_bf16(af[0][m], bf[1][n], acc[m][n], 0, 0, 0);
        acc[m][n] = __builtin_amdgcn_mfma_f32_16x16x32_bf16(af[1][m], bf[0][n], acc[m][n], 0, 0, 0);
        acc[m][n] = __builtin_amdgcn_mfma_f32_16x16x32_bf16(af[1][m], bf[1][n], acc[m][n], 0, 0, 0);
        acc[m][n] = __builtin_amdgcn_mfma_f32_16x16x32_bf16(af[0][m], bf[2][n], acc[m][n], 0, 0, 0);
        acc[m][n] = __builtin_amdgcn_mfma_f32_16x16x32_bf16(af[2][m], bf[0][n], acc[m][n], 0, 0, 0);
      }
    __syncthreads();
  }

  #pragma unroll
  for (int m = 0; m < 2; ++m)
    #pragma unroll
    for (int r = 0; r < 4; ++r) {
      int row = m0 + wr * 32 + m * 16 + kg * 4 + r;
      #pragma unroll
      for (int n = 0; n < 2; ++n) {
        int col = n0 + wc * 32 + n * 16 + r16;
        C[(long)row * H_ + col] = acc[m][n][r];
      }
    }
}

// ---------------------------------------------------------------------------
// k_G5G6: merged launch.
// blocks [0,256): G5 = S^T @ x1 (128x64 tile) + cx_bf mirror + xs0 means
// blocks [256,1280): G6' = S^T @ adj^T -> M1t bf16 (128x128 tile, XCD swz)
// ---------------------------------------------------------------------------
__global__ __launch_bounds__(256) void k_G5G6(
    const u16* __restrict__ St, const u16* __restrict__ x1T,
    float* __restrict__ out_cx, u16* __restrict__ cx_bf,
    float* __restrict__ xs0,
    const u16* __restrict__ adjBF, u16* __restrict__ M1t) {
  __shared__ __align__(16) u16 smem[128 * 64];   // 16KB shared by both paths
  const long NN = (long)N_ * N_;
  const long NH = (long)N_ * H_;
  int tid = threadIdx.x;
  int lane = tid & 63, wave = tid >> 6;
  int wr = wave >> 1, wc = wave & 1;
  int kg = lane >> 4, r16 = lane & 15;

  if ((int)blockIdx.x < 256) {
    int id = blockIdx.x;
    int bxg = id & 1, byg = (id >> 1) & 7, bz = id >> 4;
    int m0 = byg * 128, n0 = bxg * 64;
    u16* As = smem;
    u16* Bs = smem + 128 * 32;
    const u16* ga = St + (long)bz * NN + (long)(m0 + (tid >> 2)) * N_ + (tid & 3) * 8;
    const u16* gb = x1T + (long)bz * NH + (long)(n0 + (tid >> 2)) * N_ + (tid & 3) * 8;
    f32x4 acc[4][2] = {};
    for (int k0 = 0; k0 < N_; k0 += 32) {
      gload16(ga + k0, &As[tid * 8]);
      gload16(ga + (long)64 * N_ + k0, &As[2048 + tid * 8]);
      gload16(gb + k0, &Bs[tid * 8]);
      __syncthreads();
      s16x8 af[4], bf[2];
      #pragma unroll
      for (int m = 0; m < 4; ++m)
        af[m] = *(const s16x8*)(&As[(wr * 64 + m * 16 + r16) * 32 + kg * 8]);
      #pragma unroll
      for (int n = 0; n < 2; ++n)
        bf[n] = *(const s16x8*)(&Bs[(wc * 32 + n * 16 + r16) * 32 + kg * 8]);
      #pragma unroll
      for (int m = 0; m < 4; ++m)
        #pragma unroll
        for (int n = 0; n < 2; ++n)
          acc[m][n] = __builtin_amdgcn_mfma_f32_16x16x32_bf16(af[m], bf[n], acc[m][n], 0, 0, 0);
      __syncthreads();
    }
    #pragma unroll
    for (int m = 0; m < 4; ++m)
      #pragma unroll
      for (int r = 0; r < 4; ++r) {
        int row = m0 + wr * 64 + m * 16 + kg * 4 + r;
        float part = 0.f;
        #pragma unroll
        for (int n = 0; n < 2; ++n) {
          int col = n0 + wc * 32 + n * 16 + r16;
          long cidx = (long)bz * NH + (long)row * H_ + col;
          float v = acc[m][n][r];
          out_cx[cidx] = v;
          cx_bf[cidx] = f2b(v);
          part += v;
        }
        #pragma unroll
        for (int o2 = 1; o2 < 16; o2 <<= 1) part += __shfl_xor(part, o2, 64);
        if (r16 == 0) atomicAdd(&xs0[(long)bz * N_ + row], part * (1.0f / H_));
      }
  } else {
    int lin = (int)blockIdx.x - 256;
    int swz = (lin & 7) * 128 + (lin >> 3);
    int bx = swz & 7, by = (swz >> 3) & 7, bz = swz >> 6;
    int m0 = by * 128, n0 = bx * 128;
    u16* As = smem;
    u16* Bs = smem + 128 * 32;
    const u16* ga = St + (long)bz * NN + (long)(m0 + (tid >> 2)) * N_ + (tid & 3) * 8;
    const u16* gb = adjBF + (long)bz * NN + (long)(n0 + (tid >> 2)) * N_ + (tid & 3) * 8;
    f32x4 acc[4][4] = {};
    for (int k0 = 0; k0 < N_; k0 += 32) {
      gload16(ga + k0, &As[tid * 8]);
      gload16(ga + (long)64 * N_ + k0, &As[2048 + tid * 8]);
      gload16(gb + k0, &Bs[tid * 8]);
      gload16(gb + (long)64 * N_ + k0, &Bs[2048 + tid * 8]);
      __syncthreads();
      s16x8 af[4], bfr[4];
      #pragma unroll
      for (int m = 0; m < 4; ++m)
        af[m] = *(const s16x8*)(&As[(wr * 64 + m * 16 + r16) * 32 + kg * 8]);
      #pragma unroll
      for (int n = 0; n < 4; ++n)
        bfr[n] = *(const s16x8*)(&Bs[(wc * 64 + n * 16 + r16) * 32 + kg * 8]);
      #pragma unroll
      for (int m = 0; m < 4; ++m)
        #pragma unroll
        for (int n = 0; n < 4; ++n)
          acc[m][n] = __builtin_amdgcn_mfma_f32_16x16x32_bf16(af[m], bfr[n], acc[m][n], 0, 0, 0);
      __syncthreads();
    }
    #pragma unroll
    for (int m = 0; m < 4; ++m)
      #pragma unroll
      for (int r = 0; r < 4; ++r) {
        int row = m0 + wr * 64 + m * 16 + kg * 4 + r;
        #pragma unroll
        for (int n = 0; n < 4; ++n) {
          int col = n0 + wc * 64 + n * 16 + r16;
          M1t[(long)bz * NN + (long)row * N_ + col] = f2b(acc[m][n][r]);
        }
      }
  }
}

// ---------------------------------------------------------------------------
// K2: x1 = relu(dis_i*(sum_{bit j} dis_j*P1_j + dis_i*P1_i) + b1)
// bitmask compaction; 8-team f32x4 gather; fused t[row] = x1_row . Watt
// ---------------------------------------------------------------------------
__global__ __launch_bounds__(256) void k_spmm_relu(
    const u64* __restrict__ bm, const float* __restrict__ P1,
    const float* __restrict__ dis_bin, const float* __restrict__ b1,
    const float* __restrict__ Watt, float* __restrict__ x1,
    float* __restrict__ t) {
  long row = blockIdx.x;
  int b = (int)(row >> 10), i = (int)(row & 1023);
  const float* Pb = P1 + (long)b * (long)N_ * H_;
  const float* db = dis_bin + (long)b * N_;
  __shared__ int idxs[N_];
  __shared__ int wtot[4];
  __shared__ float accs[8][H_];
  int tid = threadIdx.x;
  int wid = tid >> 6, lane = tid & 63;
  int base = tid * 4;
  u64 word = bm[row * 16 + (tid >> 4)];
  int sh = base & 63;
  int f0 = (int)((word >> sh) & 1), f1 = (int)((word >> (sh + 1)) & 1);
  int f2 = (int)((word >> (sh + 2)) & 1), f3 = (int)((word >> (sh + 3)) & 1);
  int c0 = f0 + f1 + f2 + f3;
  int inc = c0;
  #pragma unroll
  for (int o = 1; o < 64; o <<= 1) {
    int v = __shfl_up(inc, o, 64);
    if (lane >= o) inc += v;
  }
  if (lane == 63) wtot[wid] = inc;
  __syncthreads();
  int wbase = 0;
  #pragma unroll
  for (int w = 0; w < 4; ++w) wbase += (w < wid) ? wtot[w] : 0;
  int pos = wbase + inc - c0;
  int n = wtot[0] + wtot[1] + wtot[2] + wtot[3];
  if (f0) idxs[pos++] = base;
  if (f1) idxs[pos++] = base + 1;
  if (f2) idxs[pos++] = base + 2;
  if (f3) idxs[pos++] = base + 3;
  __syncthreads();
  // 8-team gather: team tm handles rows u = tm, tm+8, ...; lane covers 4 ch
  int tm = tid >> 5, c4 = (tid & 31) * 4;
  f32x4 acc4 = {0.f, 0.f, 0.f, 0.f};
  for (int u = tm; u < n; u += 8) {
    int j = idxs[u];
    float w = db[j];
    f32x4 pv = *(const f32x4*)(Pb + (long)j * H_ + c4);
    acc4[0] += w * pv[0];
    acc4[1] += w * pv[1];
    acc4[2] += w * pv[2];
    acc4[3] += w * pv[3];
  }
  *(f32x4*)(&accs[tm][c4]) = acc4;
  __syncthreads();
  float v = 0.f;
  if (tid < H_) {
    int c = tid;
    float tot = 0.f;
    #pragma unroll
    for (int t8 = 0; t8 < 8; ++t8) tot += accs[t8][c];
    float di = db[i];
    tot += di * Pb[(long)i * H_ + c];
    v = fmaxf(di * tot + b1[c], 0.0f);
    x1[row * H_ + c] = v;
  }
  float prod = (tid < H_) ? v * Watt[tid] : 0.f;
  float s = blockReduceSum256(prod);
  if (tid == 0) t[row] = s;
}

// ---------------------------------------------------------------------------
// K6: blocks [0,16): alpha (inline from bitmask + LDS dt) + top-k cut + mask.
// blocks [16,2064): x1 -> x1T transpose. blocks [2064,2160): W2 -> W2T.
// ---------------------------------------------------------------------------
__global__ __launch_bounds__(1024) void k_alphacut(
    const u64* __restrict__ bm, const float* __restrict__ dis_bin,
    const float* __restrict__ t, const float* __restrict__ batt,
    const int* __restrict__ num_sent, const int* __restrict__ nout,
    float* __restrict__ index_mask, float* __restrict__ ca,
    const float* __restrict__ x1, u16* __restrict__ x1T,
    const float* __restrict__ W2, u16* __restrict__ W2T) {
  int tid = threadIdx.x;
  if (blockIdx.x >= 16) {
    // 1024-thread 32x32 transpose tile: one element per thread
    __shared__ float tile[32][33];
    int tx = tid & 31, ty = tid >> 5;
    if (blockIdx.x < 16 + 2048) {
      int id2 = blockIdx.x - 16;          // x1 [N][H] -> x1T [H][N], per batch
      int bx = id2 & 3, by = (id2 >> 2) & 31, bz = id2 >> 7;
      long NH = (long)N_ * H_;
      const float* Xb = x1 + (long)bz * NH;
      u16* Yb = x1T + (long)bz * NH;
      int r0 = by * 32, c0 = bx * 32;
      tile[ty][tx] = Xb[(long)(r0 + ty) * H_ + (c0 + tx)];
      __syncthreads();
      Yb[(long)(c0 + ty) * N_ + (r0 + tx)] = f2b(tile[tx][ty]);
    } else {
      int id3 = blockIdx.x - 16 - 2048;   // W2 [H][F] -> W2T [F][H]
      int bx = id3 % 24, by = id3 / 24;
      int r0 = by * 32, c0 = bx * 32;     // r: H dim, c: F dim
      tile[ty][tx] = W2[(long)(r0 + ty) * F_ + (c0 + tx)];
      __syncthreads();
      W2T[(long)(c0 + ty) * H_ + (r0 + tx)] = f2b(tile[tx][ty]);
    }
    return;
  }
  int b = blockIdx.x;
  __shared__ u64 keys[N_];
  __shared__ u64 red[N_];
  __shared__ float dt[N_];
  float di = dis_bin[(long)b * N_ + tid];
  float ti = t[(long)b * N_ + tid];
  dt[tid] = di * ti;
  __syncthreads();
  float s = 0.f;
  const u64* bmr = bm + ((long)b * N_ + tid) * 16;
  #pragma unroll
  for (int w = 0; w < 16; ++w) {
    u64 word = bmr[w];
    int base = w * 64;
    while (word) {
      int j = (int)__builtin_ctzll(word);
      word &= word - 1;
      s += dt[base + j];
    }
  }
  float pre = di * (s + di * ti) + batt[0];
  float z = pre * pre;
  float av = 1.0f / (1.0f + expf(-z));

  int ns = num_sent[b];
  unsigned bits = __float_as_uint(av);
  u64 keyFull = ((u64)bits << 32) | (u64)(0xFFFFFFFFu - (unsigned)tid);
  keys[tid] = (tid < ns) ? keyFull : 0ULL;
  __syncthreads();
  int k = nout[0];
  u64 cutkey = 0;
  for (int r = 0; r < k; ++r) {
    red[tid] = keys[tid];
    __syncthreads();
    for (int off = 512; off > 0; off >>= 1) {
      if (tid < off) { u64 o = red[tid + off]; if (o > red[tid]) red[tid] = o; }
      __syncthreads();
    }
    u64 mx = red[0];
    __syncthreads();
    if (r == k - 1) cutkey = mx;
    else if (keys[tid] == mx) keys[tid] = 0ULL;
    __syncthreads();
  }
  float cutalpha = __uint_as_float((unsigned)(cutkey >> 32));
  index_mask[(long)b * N_ + tid] = (keyFull >= cutkey) ? 1.0f : 0.0f;
  ca[(long)b * N_ + tid] = fmaxf(av + 1e-7f - cutalpha, 0.0f);
}

// ---------------------------------------------------------------------------
// K7: S build + L1 row-normalize (reads bf16 adj; register-resident row)
// ---------------------------------------------------------------------------
__global__ __launch_bounds__(256) void k_build_S(
    const u16* __restrict__ abf, const float* __restrict__ dr,
    const float* __restrict__ dc, const float* __restrict__ ca,
    float* __restrict__ S) {
  long row = blockIdx.x;
  int b = (int)(row >> 10), i = (int)(row & 1023);
  const u16* a = abf + row * N_;
  const float* dcb = dc + (long)b * N_;
  const float* cab = ca + (long)b * N_;
  float dri = dr[row];
  int tid = threadIdx.x;
  u16x4 av4 = *(const u16x4*)(a + tid * 4);
  f32x4 dc4 = *(const f32x4*)(dcb + tid * 4);
  f32x4 ca4 = *(const f32x4*)(cab + tid * 4);
  float ls = 0.f;
  f32x4 pv;
  #pragma unroll
  for (int e = 0; e < 4; ++e) {
    int j = tid * 4 + e;
    float avv = b2f(av4[e]) + ((j == i) ? 1.0f : 0.0f);
    float v = dri * avv * dc4[e] * ca4[e];
    pv[e] = v;
    ls += v;
  }
  float sum = blockReduceSum256(ls);
  float denom = fmaxf(sum, 1e-12f);
  f32x4 out;
  #pragma unroll
  for (int e = 0; e < 4; ++e) out[e] = pv[e] / denom;
  *(f32x4*)(&S[row * N_ + tid * 4]) = out;
}

// ---------------------------------------------------------------------------
// transpose-convert, S only: out_S [N][N] f32 -> St [N][N] bf16 (LDS-staged)
// ---------------------------------------------------------------------------
__global__ __launch_bounds__(256) void k_convTS(
    const float* __restrict__ S, u16* __restrict__ St) {
  __shared__ float tile[32][33];
  long NN = (long)N_ * N_;
  int id = blockIdx.x;
  int bx = id & 31, by = (id >> 5) & 31, bz = id >> 10;
  const float* Xb = S + (long)bz * NN;
  u16* Yb = St + (long)bz * NN;
  int tx = threadIdx.x & 31, ty = threadIdx.x >> 5;
  int r0 = by * 32, c0 = bx * 32;
  #pragma unroll
  for (int i = 0; i < 4; ++i)
    tile[ty + i * 8][tx] = Xb[(long)(r0 + ty + i * 8) * N_ + (c0 + tx)];
  __syncthreads();
  #pragma unroll
  for (int i = 0; i < 4; ++i)
    Yb[(long)(c0 + ty + i * 8) * N_ + (r0 + tx)] = f2b(tile[tx][ty + i * 8]);
}

// ---------------------------------------------------------------------------
// Big MFMA GEMM: 128x128 tile, BK=32, global_load_lds staging, XCD swizzle.
// B-operand rows (length K) at stride ldb (batch offset sB).
// MODE 2: floorq + rowcnt + cbin(diag+1) |
// 3: f32 ftanh(rsqrt(1+cnt[row])*acc + bias[col]) + xs1 atomics |
// 5: bf16 f2b(rsqrt(1+cnt[col])*acc)
// ---------------------------------------------------------------------------
template<int MODE>
__global__ __launch_bounds__(256) void mgemm(
    const u16* __restrict__ A, const u16* __restrict__ Bt, void* __restrict__ Cv,
    int M, int N, int K, long sA, long sB, long sC, long ldb,
    const int* __restrict__ cnt, const float* __restrict__ bias,
    int* __restrict__ rowcnt, u16* __restrict__ cbin,
    float* __restrict__ xsum) {
  // XCD-aware bijective chunked remap (total blocks divisible by 8)
  int gx = gridDim.x, gy = gridDim.y;
  int lin = (blockIdx.z * gy + blockIdx.y) * gx + blockIdx.x;
  int total = gx * gy * gridDim.z;
  int chunk = total >> 3;
  int swz = (lin & 7) * chunk + (lin >> 3);
  int bx = swz % gx; int t2 = swz / gx; int by = t2 % gy; int bz = t2 / gy;

  int m0 = by * 128, n0 = bx * 128;
  const u16* Ab = A + (long)bz * sA + (long)m0 * K;
  const u16* Bb = Bt + (long)bz * sB + (long)n0 * ldb;
  __shared__ __align__(16) u16 As[128 * 32];
  __shared__ __align__(16) u16 Bs[128 * 32];
  int tid = threadIdx.x;
  int lane = tid & 63, wave = tid >> 6;
  int wr = wave >> 1, wc = wave & 1;
  int kg = lane >> 4, r16 = lane & 15;
  const u16* ga = Ab + (long)(tid >> 2) * K + (tid & 3) * 8;
  const u16* gb = Bb + (long)(tid >> 2) * ldb + (tid & 3) * 8;
  f32x4 acc[4][4] = {};

  for (int k0 = 0; k0 < K; k0 += 32) {
    gload16(ga + k0, &As[tid * 8]);
    gload16(ga + (long)64 * K + k0, &As[2048 + tid * 8]);
    gload16(gb + k0, &Bs[tid * 8]);
    gload16(gb + (long)64 * ldb + k0, &Bs[2048 + tid * 8]);
    __syncthreads();
    s16x8 af[4], bfr[4];
    #pragma unroll
    for (int m = 0; m < 4; ++m)
      af[m] = *(const s16x8*)(&As[(wr * 64 + m * 16 + r16) * 32 + kg * 8]);
    #pragma unroll
    for (int n = 0; n < 4; ++n)
      bfr[n] = *(const s16x8*)(&Bs[(wc * 64 + n * 16 + r16) * 32 + kg * 8]);
    #pragma unroll
    for (int m = 0; m < 4; ++m)
      #pragma unroll
      for (int n = 0; n < 4; ++n)
        acc[m][n] = __builtin_amdgcn_mfma_f32_16x16x32_bf16(af[m], bfr[n], acc[m][n], 0, 0, 0);
    __syncthreads();
  }

  if constexpr (MODE == 2) {
    int* cntl = (int*)As;
    if (tid < 128) cntl[tid] = 0;
    __syncthreads();
    #pragma unroll
    for (int m = 0; m < 4; ++m) {
      #pragma unroll
      for (int r = 0; r < 4; ++r) {
        int lrow = wr * 64 + m * 16 + kg * 4 + r;
        int row = m0 + lrow;
        int nz = 0;
        #pragma unroll
        for (int n = 0; n < 4; ++n) {
          int col = n0 + wc * 64 + n * 16 + r16;
          float q = floorf(acc[m][n][r] * 10000.0f) / 10000.0f;
          long cidx = (long)bz * sC + (long)row * N + col;
          ((float*)Cv)[cidx] = q;
          bool qnz = (q != 0.0f);
          u16 bv;
          if (row == col) bv = qnz ? (u16)0x4000 : (u16)0x3F80;  // bin+I diag
          else            bv = qnz ? (u16)0x3F80 : (u16)0;
          cbin[cidx] = bv;
          nz += qnz ? 1 : 0;
        }
        atomicAdd(&cntl[lrow], nz);
      }
    }
    __syncthreads();
    if (tid < 128) atomicAdd(&rowcnt[(long)bz * N_ + m0 + tid], cntl[tid]);
    return;
  }

  #pragma unroll
  for (int m = 0; m < 4; ++m) {
    #pragma unroll
    for (int r = 0; r < 4; ++r) {
      int row = m0 + wr * 64 + m * 16 + kg * 4 + r;
      float sc = 0.f;
      if constexpr (MODE == 3)
        sc = rsqrtf(1.0f + (float)cnt[(long)bz * N_ + row]);
      float part = 0.f;
      #pragma unroll
      for (int n = 0; n < 4; ++n) {
        int col = n0 + wc * 64 + n * 16 + r16;
        float v = acc[m][n][r];
        long cidx = (long)bz * sC + (long)row * N + col;
        if constexpr (MODE == 3) {
          float th = ftanh(sc * v + bias[col]);
          ((float*)Cv)[cidx] = th;
          part += th;
        } else if constexpr (MODE == 5) {
          float scc = rsqrtf(1.0f + (float)cnt[col]);
          ((u16*)Cv)[cidx] = f2b(scc * v);
        } else {
          ((float*)Cv)[cidx] = v;
        }
      }
      if constexpr (MODE == 3) {
        #pragma unroll
        for (int o2 = 1; o2 < 16; o2 <<= 1) part += __shfl_xor(part, o2, 64);
        if (r16 == 0) atomicAdd(&xsum[(long)bz * N_ + row], part * (1.0f / F_));
      }
    }
  }
}

// ---------------------------------------------------------------------------
extern "C" void kernel_launch(void* const* d_in, const int* in_sizes, int n_in,
                              void* d_out, int out_size, void* d_ws, size_t ws_size,
                              hipStream_t stream) {
  const float* x     = (const float*)d_in[0];
  const float* adj   = (const float*)d_in[1];
  const int*   nsent = (const int*)d_in[2];
  const float* W1    = (const float*)d_in[3];
  const float* b1    = (const float*)d_in[4];
  const float* Watt  = (const float*)d_in[5];
  const float* batt  = (const float*)d_in[6];
  const float* W2    = (const float*)d_in[7];
  const float* b2    = (const float*)d_in[8];
  const int*   nout  = (const int*)d_in[9];

  const long NN = (long)N_ * N_;
  const long NH = (long)N_ * H_;
  const long NF = (long)N_ * F_;
  const int BN = B_ * N_;

  // output layout (flat concat, f32)
  float* out_x2   = (float*)d_out;
  float* out_cx   = out_x2 + (long)B_ * NF;
  float* out_cadj = out_cx + (long)B_ * NH;
  float* out_S    = out_cadj + (long)B_ * NN;
  float* out_im   = out_S + (long)B_ * NN;
  float* out_xs0  = out_im + BN;
  float* out_xs1  = out_xs0 + BN;

  // workspace
  char* wsb = (char*)d_ws;
  float* P1      = (float*)wsb;
  float* x1      = P1 + (long)B_ * NH;
  float* t       = x1 + (long)B_ * NH;
  float* alpha   = t + BN;
  float* dis_bin = alpha + BN;
  float* dr      = dis_bin + BN;
  float* dc      = dr + BN;
  float* ca      = dc + BN;
  int*   rowcnt  = (int*)(ca + BN);
  u64*   bm      = (u64*)(rowcnt + BN);       // 2MB bitmask
  char*  p       = (char*)(bm + (long)BN * 16);
  p = (char*)(((size_t)p + 255) & ~(size_t)255);
  u16* W1h   = (u16*)p;  p += (long)H_ * F_ * 2;
  u16* W1m   = (u16*)p;  p += (long)H_ * F_ * 2;
  u16* W1l   = (u16*)p;  p += (long)H_ * F_ * 2;
  u16* W2T   = (u16*)p;  p += (long)H_ * F_ * 2;
  u16* PT    = (u16*)p;  p += (long)B_ * NH * 2;   // x1T
  u16* St    = (u16*)p;  p += (long)B_ * NN * 2;   // St -> P2T
  u16* wsB   = (u16*)p;  p += (long)B_ * NN * 2;   // cbin
  u16* cx_bf = (u16*)P1;         // P1 dead after spmm
  u16* x1T   = PT;
  u16* adjBF = (u16*)out_cadj;   // lives in out_cadj region until G7' writes it
  u16* cbin  = wsB;              // written by G7'
  u16* P2T   = St;               // St dead after G7'
  u16* M1t   = (u16*)out_x2;     // scratch in unwritten output region (32MB)
  (void)alpha;

  // K0: transpose-split W1 + degrees/bitmask/adj_bf/rowcnt/xs-zero
  k_prep<<<dim3(96 + BN), dim3(256), 0, stream>>>(
      W1, W1h, W1m, W1l,
      adj, dis_bin, dr, dc, bm, adjBF, rowcnt, out_xs0, out_xs1);

  // G1: P1raw = x @ W1  (in-register split-3 from f32 x; 64x64 tile)
  mgemmG1<<<dim3(H_ / 64, BN / 64, 1), dim3(256), 0, stream>>>(
      x, W1h, W1m, W1l, P1);

  // K2: x1 + fused t (bitmask, 8-team f32x4 gather)
  k_spmm_relu<<<dim3(BN), dim3(256), 0, stream>>>(bm, P1, dis_bin, b1, Watt, x1, t);

  // alpha (inline) + top-k cut/mask, co-scheduled with x1T/W2T transposes
  k_alphacut<<<dim3(16 + 2048 + 96), dim3(1024), 0, stream>>>(
      bm, dis_bin, t, batt, nsent, nout, out_im, ca, x1, x1T, W2, W2T);

  // S from bf16 adj
  k_build_S<<<dim3(BN), dim3(256), 0, stream>>>(adjBF, dr, dc, ca, out_S);

  // S transpose only
  k_convTS<<<dim3(16384), dim3(256), 0, stream>>>(out_S, St);

  // G5+G6' merged: coarse_x (+cx_bf, xs0) and M1t = (adj @ S)^T
  k_G5G6<<<dim3(256 + 1024), dim3(256), 0, stream>>>(
      St, x1T, out_cx, cx_bf, out_xs0, adjBF, M1t);

  // G7': coarse_adj = floorq(S^T @ M1) + rowcnt + cbin(diag+1)
  mgemm<2><<<dim3(N_ / 128, N_ / 128, B_), dim3(256), 0, stream>>>(
      St, M1t, out_cadj, N_, N_, N_, NN, NN, NN, N_, nullptr, nullptr, rowcnt,
      cbin, nullptr);

  // G8' (transposed role): P2T[f][r] = f2b(rsqrt(1+cnt[r]) * (W2T[f] . cx_bf[r]))
  mgemm<5><<<dim3(BN / 128, F_ / 128, 1), dim3(256), 0, stream>>>(
      W2T, cx_bf, P2T, F_, BN, H_, 0, 0, 0, H_, rowcnt, nullptr, nullptr,
      nullptr, nullptr);

  // G9: x2 = ftanh(rsqrt(1+cnt[row]) * (cbin' @ P2) + b2) + xs1 row-means
  mgemm<3><<<dim3(F_ / 128, N_ / 128, B_), dim3(256), 0, stream>>>(
      cbin, P2T, out_x2, N_, F_, N_, NN, N_, NF, (long)BN, rowcnt, b2,
      nullptr, nullptr, out_xs1);
}